// Round 7
// baseline (492.545 us; speedup 1.0000x reference)
//
#include <hip/hip_runtime.h>
#include <cstdint>
#include <cstddef>

// GCN link prediction: 3x GCNConv(64->64) + ReLU, then 2-layer MLP head.
// N=100k, E=1M, dims 64. Round 7:
//  - Activations stored pre-scaled: hws = (h @ W) * dinv[row]. Then
//    agg = dinv[d]*(sum_src hws[src] + hws[d]) + b  -> edge records are bare
//    src ints (4 B): k_fill scatter halves, no per-edge norm gathers.
//  - agg and the following matmul are FUSED (3x): per 16-node tile, gather-
//    aggregate each node, bias+relu, transpose via LDS into MFMA A-layout,
//    24 split-bf16 MFMAs, epilogue (scale-by-dinv or +bias+relu), store.
//  - Standalone mm only for layer1 (x@W1 -> *dinv) and the final head mm.

#define CDIV(a, b) (((a) + (b) - 1) / (b))
static constexpr int SCAN_B = 1024;

typedef __attribute__((ext_vector_type(8))) short bf16x8;
typedef __attribute__((ext_vector_type(4))) float f32x4;

// Split a into hi (RNE bf16) + lo (truncated bf16 of exact residual).
__device__ __forceinline__ void split_bf(float a, short& hi, short& lo) {
  unsigned u = __float_as_uint(a);
  unsigned r = u + (0x7FFF + ((u >> 16) & 1));  // RNE round to bf16
  hi = (short)(r >> 16);
  float hirec = __uint_as_float(r & 0xFFFF0000u);
  float res = a - hirec;  // exact
  lo = (short)(__float_as_uint(res) >> 16);  // truncate
}

__global__ void k_zero_i32(int* __restrict__ p, int n) {
  int i = blockIdx.x * blockDim.x + threadIdx.x;
  if (i < n) p[i] = 0;
}

__global__ void k_count(const int* __restrict__ ei, int* __restrict__ counts, int E) {
  int e = blockIdx.x * blockDim.x + threadIdx.x;
  if (e < E) atomicAdd(&counts[ei[E + e]], 1);
}

__global__ void k_dinv(const int* __restrict__ counts, float* __restrict__ dinv, int n) {
  int i = blockIdx.x * blockDim.x + threadIdx.x;
  if (i < n) dinv[i] = rsqrtf((float)counts[i] + 1.0f);
}

// Inclusive block scan (Hillis-Steele) -> exclusive output + per-block sums.
__global__ void k_scan1(const int* __restrict__ counts, int* __restrict__ excl,
                        int* __restrict__ bsums, int n) {
  __shared__ int sh[SCAN_B];
  int t = threadIdx.x;
  int idx = blockIdx.x * SCAN_B + t;
  int v = (idx < n) ? counts[idx] : 0;
  int val = v;
  sh[t] = val;
  __syncthreads();
  for (int off = 1; off < SCAN_B; off <<= 1) {
    int add = (t >= off) ? sh[t - off] : 0;
    __syncthreads();
    val += add;
    sh[t] = val;
    __syncthreads();
  }
  if (idx < n) excl[idx] = val - v;
  if (t == SCAN_B - 1) bsums[blockIdx.x] = val;
}

__global__ void k_scan2(int* __restrict__ bsums, int nb) {
  __shared__ int sh[SCAN_B];
  int t = threadIdx.x;
  int v = (t < nb) ? bsums[t] : 0;
  int val = v;
  sh[t] = val;
  __syncthreads();
  for (int off = 1; off < SCAN_B; off <<= 1) {
    int add = (t >= off) ? sh[t - off] : 0;
    __syncthreads();
    val += add;
    sh[t] = val;
    __syncthreads();
  }
  if (t < nb) bsums[t] = val - v;
}

__global__ void k_scan3(int* __restrict__ row_ptr, const int* __restrict__ bsums,
                        int* __restrict__ counts, int n, int E) {
  int i = blockIdx.x * blockDim.x + threadIdx.x;
  if (i < n) {
    row_ptr[i] += bsums[i >> 10];  // SCAN_B == 1024
    counts[i] = 0;                 // reuse as fill cursors
  }
  if (i == 0) row_ptr[n] = E;
}

// Scatter src ids into dst-sorted order. 4 B records (no norm — activations
// are pre-scaled by dinv, so agg needs only src).
__global__ void k_fill(const int* __restrict__ ei, const int* __restrict__ row_ptr,
                       int* __restrict__ counts, int* __restrict__ srcs, int E) {
  int e = blockIdx.x * blockDim.x + threadIdx.x;
  if (e >= E) return;
  int s = ei[e];
  int d = ei[E + e];
  int pos = row_ptr[d] + atomicAdd(&counts[d], 1);
  srcs[pos] = s;
}

// Pre-split 5 weight matrices (64x64, [in,out] row-major) into hi/lo bf16
// fragments, packed: packed[mat*1024 + ((t*2+q)*2+h)*64 + lane].
__global__ void k_prep(const float* __restrict__ w0, const float* __restrict__ w1,
                       const float* __restrict__ w2, const float* __restrict__ w3,
                       const float* __restrict__ w4, bf16x8* __restrict__ packed) {
  const float* W;
  switch (blockIdx.x) {
    case 0: W = w0; break;
    case 1: W = w1; break;
    case 2: W = w2; break;
    case 3: W = w3; break;
    default: W = w4; break;
  }
  int tid = threadIdx.x;  // 0..511
  int lane = tid & 63;
  int q = (tid >> 6) & 1;
  int t = tid >> 7;
  int col = lane & 15, quad = lane >> 4;
  bf16x8 hi8, lo8;
#pragma unroll
  for (int j = 0; j < 8; ++j) {
    int k = q * 32 + quad * 8 + j;
    short hi, lo;
    split_bf(W[k * 64 + t * 16 + col], hi, lo);
    hi8[j] = hi;
    lo8[j] = lo;
  }
  size_t base = (size_t)blockIdx.x * 1024 + ((t * 2 + q) * 2) * 64 + lane;
  packed[base] = hi8;
  packed[base + 64] = lo8;
}

// Standalone mm: C[n x 64] = A @ W (+bias) (optionally *dinv[row]).
// One wave per 16-row tile, grid-stride. Verified layouts:
// A[m=lane&15][k=quad*8+j]; B[k][n=lane&15]; C col=lane&15,row=quad*4+reg.
template <bool HAS_BIAS, bool DINV_OUT>
__global__ __launch_bounds__(256, 4)
void k_mm_mfma(const float* __restrict__ in, const bf16x8* __restrict__ Wp,
               const float* __restrict__ bias, const float* __restrict__ dinv,
               float* __restrict__ out, int n) {
  int lane = threadIdx.x & 63;
  int col = lane & 15, quad = lane >> 4;
  int wid = (blockIdx.x * blockDim.x + threadIdx.x) >> 6;
  int nw = (gridDim.x * blockDim.x) >> 6;
  int ntiles = (n + 15) >> 4;

  bf16x8 wh[4][2], wl[4][2];
#pragma unroll
  for (int t = 0; t < 4; ++t)
#pragma unroll
    for (int q = 0; q < 2; ++q) {
      wh[t][q] = Wp[((t * 2 + q) * 2) * 64 + lane];
      wl[t][q] = Wp[((t * 2 + q) * 2 + 1) * 64 + lane];
    }
  float bv[4];
#pragma unroll
  for (int t = 0; t < 4; ++t) bv[t] = HAS_BIAS ? bias[t * 16 + col] : 0.0f;

  for (int tile = wid; tile < ntiles; tile += nw) {
    int row0 = tile << 4;
    int ar = row0 + col;
    if (ar > n - 1) ar = n - 1;
    const float4* arow = (const float4*)(in + (size_t)ar * 64 + quad * 8);
    bf16x8 ah[2], al[2];
#pragma unroll
    for (int q = 0; q < 2; ++q) {
      float4 v0 = arow[q * 8 + 0];
      float4 v1 = arow[q * 8 + 1];
      float av[8] = {v0.x, v0.y, v0.z, v0.w, v1.x, v1.y, v1.z, v1.w};
#pragma unroll
      for (int j = 0; j < 8; ++j) {
        short hi, lo;
        split_bf(av[j], hi, lo);
        ah[q][j] = hi;
        al[q][j] = lo;
      }
    }
    f32x4 acc[4];
#pragma unroll
    for (int t = 0; t < 4; ++t) acc[t] = (f32x4){0.f, 0.f, 0.f, 0.f};
#pragma unroll
    for (int t = 0; t < 4; ++t)
#pragma unroll
      for (int q = 0; q < 2; ++q) {
        acc[t] = __builtin_amdgcn_mfma_f32_16x16x32_bf16(ah[q], wh[t][q], acc[t], 0, 0, 0);
        acc[t] = __builtin_amdgcn_mfma_f32_16x16x32_bf16(ah[q], wl[t][q], acc[t], 0, 0, 0);
        acc[t] = __builtin_amdgcn_mfma_f32_16x16x32_bf16(al[q], wh[t][q], acc[t], 0, 0, 0);
      }
    float dv[4];
    if (DINV_OUT) {
#pragma unroll
      for (int r = 0; r < 4; ++r) {
        int row = row0 + quad * 4 + r;
        dv[r] = (row < n) ? dinv[row] : 0.0f;
      }
    }
#pragma unroll
    for (int t = 0; t < 4; ++t)
#pragma unroll
      for (int r = 0; r < 4; ++r) {
        int row = row0 + quad * 4 + r;
        if (row < n) {
          float v = acc[t][r] + bv[t];
          if (DINV_OUT) v *= dv[r];
          out[(size_t)row * 64 + t * 16 + col] = v;
        }
      }
  }
}

// Fused agg -> mm. One wave per 16-node tile (exactly one tile per wave).
// Phase 1: per node, gather-sum pre-scaled rows hws[src] (4 slots x 16 lanes
//   x float4), then h = relu(dinv[node]*(sum + hws[node]) + bias_agg),
//   slot0 stores the row to LDS (stride 68 floats: 2-way banks only).
// Phase 2: __syncthreads (uniform trip count — no early returns before it).
// Phase 3: lanes read A-fragments from LDS, split-bf16, 24 MFMAs, epilogue:
//   LAST ? relu(C + bias_out) : C * dinv[row]; store.
template <bool LAST>
__global__ __launch_bounds__(256, 4)
void k_fused(const float* __restrict__ hws, const float* __restrict__ dinv,
             const int* __restrict__ row_ptr, const int* __restrict__ srcs,
             const float* __restrict__ bias_agg, const bf16x8* __restrict__ Wp,
             const float* __restrict__ bias_out, float* __restrict__ out, int n) {
  __shared__ float lds[4][16 * 68];
  int lane = threadIdx.x & 63;
  int col = lane & 15, quad = lane >> 4;
  int slot = lane >> 4;  // alias of quad, used in gather phase
  int fg = lane & 15;
  int wv = threadIdx.x >> 6;
  int tile = (blockIdx.x * blockDim.x + threadIdx.x) >> 6;
  int ntiles = (n + 15) >> 4;
  int row0 = tile << 4;
  const float4* hws4 = (const float4*)hws;
  float* lw = &lds[wv][0];

  // W fragments for the following matmul
  bf16x8 wh[4][2], wl[4][2];
#pragma unroll
  for (int t = 0; t < 4; ++t)
#pragma unroll
    for (int q = 0; q < 2; ++q) {
      wh[t][q] = Wp[((t * 2 + q) * 2) * 64 + lane];
      wl[t][q] = Wp[((t * 2 + q) * 2 + 1) * 64 + lane];
    }

  // row_ptr[row0 .. row0+16] via one coalesced load + readlane broadcast
  int rp = 0;
  if (tile < ntiles && lane < 17) {
    int idx = row0 + lane;
    if (idx > n) idx = n;
    rp = row_ptr[idx];
  }
  float4 b4 = make_float4(0.f, 0.f, 0.f, 0.f);
  if (tile < ntiles) b4 = ((const float4*)bias_agg)[fg];

#pragma unroll 1
  for (int i = 0; i < 16; ++i) {
    int p0 = __builtin_amdgcn_readlane(rp, i);
    int p1 = __builtin_amdgcn_readlane(rp, i + 1);
    float4 acc = make_float4(0.f, 0.f, 0.f, 0.f);
    for (int p = p0 + slot; p < p1; p += 4) {
      int s = srcs[p];
      float4 v = hws4[(size_t)s * 16 + fg];
      acc.x += v.x; acc.y += v.y; acc.z += v.z; acc.w += v.w;
    }
#pragma unroll
    for (int off = 16; off < 64; off <<= 1) {
      acc.x += __shfl_xor(acc.x, off);
      acc.y += __shfl_xor(acc.y, off);
      acc.z += __shfl_xor(acc.z, off);
      acc.w += __shfl_xor(acc.w, off);
    }
    int node = row0 + i;
    if (slot == 0 && node < n) {
      float di = dinv[node];
      float4 selfv = hws4[(size_t)node * 16 + fg];
      float4 r;
      r.x = fmaxf(fmaf(di, acc.x + selfv.x, b4.x), 0.f);
      r.y = fmaxf(fmaf(di, acc.y + selfv.y, b4.y), 0.f);
      r.z = fmaxf(fmaf(di, acc.z + selfv.z, b4.z), 0.f);
      r.w = fmaxf(fmaf(di, acc.w + selfv.w, b4.w), 0.f);
      *(float4*)&lw[i * 68 + fg * 4] = r;
    }
  }

  __syncthreads();  // every wave reaches this exactly once

  if (tile >= ntiles) return;

  // Phase 3: A-fragments from LDS (row m=col, k=q*32+quad*8+j)
  bf16x8 ah[2], al[2];
#pragma unroll
  for (int q = 0; q < 2; ++q) {
    const float* lr = &lw[col * 68 + q * 32 + quad * 8];
#pragma unroll
    for (int j = 0; j < 8; ++j) {
      short hi, lo;
      split_bf(lr[j], hi, lo);
      ah[q][j] = hi;
      al[q][j] = lo;
    }
  }
  f32x4 acc[4];
#pragma unroll
  for (int t = 0; t < 4; ++t) acc[t] = (f32x4){0.f, 0.f, 0.f, 0.f};
#pragma unroll
  for (int t = 0; t < 4; ++t)
#pragma unroll
    for (int q = 0; q < 2; ++q) {
      acc[t] = __builtin_amdgcn_mfma_f32_16x16x32_bf16(ah[q], wh[t][q], acc[t], 0, 0, 0);
      acc[t] = __builtin_amdgcn_mfma_f32_16x16x32_bf16(ah[q], wl[t][q], acc[t], 0, 0, 0);
      acc[t] = __builtin_amdgcn_mfma_f32_16x16x32_bf16(al[q], wh[t][q], acc[t], 0, 0, 0);
    }

  float bo[4];
  float dv[4];
#pragma unroll
  for (int r = 0; r < 4; ++r) {
    int row = row0 + quad * 4 + r;
    if (LAST) {
      dv[r] = 0.f;
    } else {
      dv[r] = (row < n) ? dinv[row] : 0.0f;
    }
  }
#pragma unroll
  for (int t = 0; t < 4; ++t) bo[t] = LAST ? bias_out[t * 16 + col] : 0.0f;

#pragma unroll
  for (int t = 0; t < 4; ++t)
#pragma unroll
    for (int r = 0; r < 4; ++r) {
      int row = row0 + quad * 4 + r;
      if (row < n) {
        float v;
        if (LAST) {
          v = fmaxf(acc[t][r] + bo[t], 0.0f);
        } else {
          v = acc[t][r] * dv[r];
        }
        out[(size_t)row * 64 + t * 16 + col] = v;
      }
    }
}

extern "C" void kernel_launch(void* const* d_in, const int* in_sizes, int n_in,
                              void* d_out, int out_size, void* d_ws, size_t ws_size,
                              hipStream_t stream) {
  const float* x = (const float*)d_in[0];
  const int* ei = (const int*)d_in[1];  // int32 per harness convention
  const float* W1 = (const float*)d_in[2];
  const float* b1 = (const float*)d_in[3];
  const float* W2 = (const float*)d_in[4];
  const float* b2 = (const float*)d_in[5];
  const float* W3 = (const float*)d_in[6];
  const float* b3 = (const float*)d_in[7];
  const float* fw1 = (const float*)d_in[8];
  const float* fb1 = (const float*)d_in[9];
  const float* fw2 = (const float*)d_in[10];
  const float* fb2 = (const float*)d_in[11];
  float* out = (float*)d_out;

  const int N = in_sizes[0] / 64;
  const int E = in_sizes[1] / 2;

  // workspace (~31 MB); d_out doubles as ping-pong activation buffer
  char* w = (char*)d_ws;
  auto take = [&](size_t bytes) -> char* {
    char* p = w;
    w += (bytes + 255) & ~(size_t)255;
    return p;
  };
  float* dinv = (float*)take((size_t)N * 4);
  int* counts = (int*)take((size_t)N * 4);
  int* row_ptr = (int*)take((size_t)(N + 1) * 4);
  int* bsums = (int*)take((size_t)SCAN_B * 4);
  int* srcs = (int*)take((size_t)E * 4);
  bf16x8* wpack = (bf16x8*)take((size_t)5 * 1024 * 16);  // 80 KB
  float* buf0 = (float*)take((size_t)N * 64 * 4);
  float* buf1 = out;  // overwritten fully by the final mm

  const int B = 256;
  const int nb_scan = CDIV(N, SCAN_B);

  // ---- weight prep + CSR build + degrees ----
  k_prep<<<5, 512, 0, stream>>>(W1, W2, W3, fw1, fw2, wpack);
  k_zero_i32<<<CDIV(N, B), B, 0, stream>>>(counts, N);
  k_count<<<CDIV(E, B), B, 0, stream>>>(ei, counts, E);
  k_dinv<<<CDIV(N, B), B, 0, stream>>>(counts, dinv, N);
  k_scan1<<<nb_scan, SCAN_B, 0, stream>>>(counts, row_ptr, bsums, N);
  k_scan2<<<1, SCAN_B, 0, stream>>>(bsums, nb_scan);
  k_scan3<<<CDIV(N, B), B, 0, stream>>>(row_ptr, bsums, counts, N, E);
  k_fill<<<CDIV(E, B), B, 0, stream>>>(ei, row_ptr, counts, srcs, E);

  const int ntiles = CDIV(N, 16);
  const int MMG = CDIV(ntiles, 4);  // 1 tile/wave
  const int FG = CDIV(ntiles, 4);   // 1 tile/wave (fused)

  // hws1 = (x@W1)*dinv -> buf0
  k_mm_mfma<false, true><<<MMG, B, 0, stream>>>(x, wpack + 0 * 1024, nullptr, dinv, buf0, N);
  // fused: agg(hws1)+b1,relu -> @W2 -> *dinv -> buf1
  k_fused<false><<<FG, B, 0, stream>>>(buf0, dinv, row_ptr, srcs, b1, wpack + 1 * 1024, nullptr, buf1, N);
  // fused: agg(hws2)+b2,relu -> @W3 -> *dinv -> buf0
  k_fused<false><<<FG, B, 0, stream>>>(buf1, dinv, row_ptr, srcs, b2, wpack + 2 * 1024, nullptr, buf0, N);
  // fused: agg(hws3)+b3,relu -> @fw1 -> +fb1,relu -> buf1
  k_fused<true><<<FG, B, 0, stream>>>(buf0, dinv, row_ptr, srcs, b3, wpack + 3 * 1024, fb1, buf1, N);
  // out = h4@fw2 + fb2 (in==out safe: each wave reads only its own rows)
  k_mm_mfma<true, false><<<MMG, B, 0, stream>>>(buf1, wpack + 4 * 1024, fb2, nullptr, out, N);
}

// Round 8
// 468.352 us; speedup vs baseline: 1.0517x; 1.0517x over previous
//
#include <hip/hip_runtime.h>
#include <cstdint>
#include <cstddef>

// GCN link prediction: 3x GCNConv(64->64) + ReLU, then 2-layer MLP head.
// N=100k, E=1M, dims 64. Round 8: revert round-7 fusion (it serialized the
// edge gather 16x -> latency-bound). Keep pre-scaled activations
// (hws = h*dinv) + 4 B edge records. k_agg: one node/wave, 4 slots x 16
// lanes x float4, 2x unrolled (8 gathers in flight). k_fill: cursors
// pre-initialized to row_ptr (no per-edge row_ptr gather). k_mm: 2 tiles
// per wave, both A loads issued up front.

#define CDIV(a, b) (((a) + (b) - 1) / (b))
static constexpr int SCAN_B = 1024;

typedef __attribute__((ext_vector_type(8))) short bf16x8;
typedef __attribute__((ext_vector_type(4))) float f32x4;

// Split a into hi (RNE bf16) + lo (truncated bf16 of exact residual).
__device__ __forceinline__ void split_bf(float a, short& hi, short& lo) {
  unsigned u = __float_as_uint(a);
  unsigned r = u + (0x7FFF + ((u >> 16) & 1));  // RNE round to bf16
  hi = (short)(r >> 16);
  float hirec = __uint_as_float(r & 0xFFFF0000u);
  float res = a - hirec;  // exact
  lo = (short)(__float_as_uint(res) >> 16);  // truncate
}

__global__ void k_zero_i32(int* __restrict__ p, int n) {
  int i = blockIdx.x * blockDim.x + threadIdx.x;
  if (i < n) p[i] = 0;
}

__global__ void k_count(const int* __restrict__ ei, int* __restrict__ counts, int E) {
  int e = blockIdx.x * blockDim.x + threadIdx.x;
  if (e < E) atomicAdd(&counts[ei[E + e]], 1);
}

// Inclusive block scan (Hillis-Steele) -> exclusive output + per-block sums.
// Also emits dinv = rsqrt(count+1) (folded degree kernel).
__global__ void k_scan1(const int* __restrict__ counts, int* __restrict__ excl,
                        int* __restrict__ bsums, float* __restrict__ dinv, int n) {
  __shared__ int sh[SCAN_B];
  int t = threadIdx.x;
  int idx = blockIdx.x * SCAN_B + t;
  int v = (idx < n) ? counts[idx] : 0;
  if (idx < n) dinv[idx] = rsqrtf((float)v + 1.0f);
  int val = v;
  sh[t] = val;
  __syncthreads();
  for (int off = 1; off < SCAN_B; off <<= 1) {
    int add = (t >= off) ? sh[t - off] : 0;
    __syncthreads();
    val += add;
    sh[t] = val;
    __syncthreads();
  }
  if (idx < n) excl[idx] = val - v;
  if (t == SCAN_B - 1) bsums[blockIdx.x] = val;
}

__global__ void k_scan2(int* __restrict__ bsums, int nb) {
  __shared__ int sh[SCAN_B];
  int t = threadIdx.x;
  int v = (t < nb) ? bsums[t] : 0;
  int val = v;
  sh[t] = val;
  __syncthreads();
  for (int off = 1; off < SCAN_B; off <<= 1) {
    int add = (t >= off) ? sh[t - off] : 0;
    __syncthreads();
    val += add;
    sh[t] = val;
    __syncthreads();
  }
  if (t < nb) bsums[t] = val - v;
}

// Finalize row_ptr and initialize fill cursors to row_ptr (so k_fill needs
// no separate row_ptr gather).
__global__ void k_scan3(int* __restrict__ row_ptr, const int* __restrict__ bsums,
                        int* __restrict__ cursors, int n, int E) {
  int i = blockIdx.x * blockDim.x + threadIdx.x;
  if (i < n) {
    int rp = row_ptr[i] + bsums[i >> 10];  // SCAN_B == 1024
    row_ptr[i] = rp;
    cursors[i] = rp;
  }
  if (i == 0) row_ptr[n] = E;
}

// Scatter src ids into dst-sorted order; cursors pre-initialized to row_ptr.
__global__ void k_fill(const int* __restrict__ ei, int* __restrict__ cursors,
                       int* __restrict__ srcs, int E) {
  int e = blockIdx.x * blockDim.x + threadIdx.x;
  if (e >= E) return;
  int s = ei[e];
  int d = ei[E + e];
  int pos = atomicAdd(&cursors[d], 1);
  srcs[pos] = s;
}

// Pre-split 5 weight matrices (64x64, [in,out] row-major) into hi/lo bf16
// fragments, packed: packed[mat*1024 + ((t*2+q)*2+h)*64 + lane].
__global__ void k_prep(const float* __restrict__ w0, const float* __restrict__ w1,
                       const float* __restrict__ w2, const float* __restrict__ w3,
                       const float* __restrict__ w4, bf16x8* __restrict__ packed) {
  const float* W;
  switch (blockIdx.x) {
    case 0: W = w0; break;
    case 1: W = w1; break;
    case 2: W = w2; break;
    case 3: W = w3; break;
    default: W = w4; break;
  }
  int tid = threadIdx.x;  // 0..511
  int lane = tid & 63;
  int q = (tid >> 6) & 1;
  int t = tid >> 7;
  int col = lane & 15, quad = lane >> 4;
  bf16x8 hi8, lo8;
#pragma unroll
  for (int j = 0; j < 8; ++j) {
    int k = q * 32 + quad * 8 + j;
    short hi, lo;
    split_bf(W[k * 64 + t * 16 + col], hi, lo);
    hi8[j] = hi;
    lo8[j] = lo;
  }
  size_t base = (size_t)blockIdx.x * 1024 + ((t * 2 + q) * 2) * 64 + lane;
  packed[base] = hi8;
  packed[base + 64] = lo8;
}

// C[n x 64] = A @ W (+bias) (+relu) (optionally * dinv[row]).
// TWO 16-row tiles per wave; both A-tile loads issued before any compute.
// Verified layouts: A[m=lane&15][k=quad*8+j]; B[k][n=lane&15];
// C col=lane&15, row=quad*4+reg.
template <bool HAS_BIAS, bool RELU_OUT, bool DINV_OUT>
__global__ __launch_bounds__(256, 3)
void k_mm(const float* __restrict__ in, const bf16x8* __restrict__ Wp,
          const float* __restrict__ bias, const float* __restrict__ dinv,
          float* __restrict__ out, int n) {
  int lane = threadIdx.x & 63;
  int col = lane & 15, quad = lane >> 4;
  int wid = (blockIdx.x * blockDim.x + threadIdx.x) >> 6;
  int ntiles = (n + 15) >> 4;
  int tile0 = wid * 2;
  if (tile0 >= ntiles) return;

  bf16x8 wh[4][2], wl[4][2];
#pragma unroll
  for (int t = 0; t < 4; ++t)
#pragma unroll
    for (int q = 0; q < 2; ++q) {
      wh[t][q] = Wp[((t * 2 + q) * 2) * 64 + lane];
      wl[t][q] = Wp[((t * 2 + q) * 2 + 1) * 64 + lane];
    }
  float bv[4];
#pragma unroll
  for (int t = 0; t < 4; ++t) bv[t] = HAS_BIAS ? bias[t * 16 + col] : 0.0f;

  // Issue both tiles' A loads up front (independent, 2x mem parallelism).
  float4 areg[2][4];
  int ntl = (tile0 + 1 < ntiles) ? 2 : 1;
#pragma unroll
  for (int tt = 0; tt < 2; ++tt) {
    if (tt < ntl) {
      int ar = (tile0 + tt) * 16 + col;
      if (ar > n - 1) ar = n - 1;
      const float4* arow = (const float4*)(in + (size_t)ar * 64 + quad * 8);
      areg[tt][0] = arow[0];
      areg[tt][1] = arow[1];
      areg[tt][2] = arow[8];
      areg[tt][3] = arow[9];
    }
  }

  for (int tt = 0; tt < ntl; ++tt) {
    int row0 = (tile0 + tt) << 4;
    bf16x8 ah[2], al[2];
#pragma unroll
    for (int q = 0; q < 2; ++q) {
      float4 v0 = areg[tt][q * 2 + 0];
      float4 v1 = areg[tt][q * 2 + 1];
      float av[8] = {v0.x, v0.y, v0.z, v0.w, v1.x, v1.y, v1.z, v1.w};
#pragma unroll
      for (int j = 0; j < 8; ++j) {
        short hi, lo;
        split_bf(av[j], hi, lo);
        ah[q][j] = hi;
        al[q][j] = lo;
      }
    }
    f32x4 acc[4];
#pragma unroll
    for (int t = 0; t < 4; ++t) acc[t] = (f32x4){0.f, 0.f, 0.f, 0.f};
#pragma unroll
    for (int t = 0; t < 4; ++t)
#pragma unroll
      for (int q = 0; q < 2; ++q) {
        acc[t] = __builtin_amdgcn_mfma_f32_16x16x32_bf16(ah[q], wh[t][q], acc[t], 0, 0, 0);
        acc[t] = __builtin_amdgcn_mfma_f32_16x16x32_bf16(ah[q], wl[t][q], acc[t], 0, 0, 0);
        acc[t] = __builtin_amdgcn_mfma_f32_16x16x32_bf16(al[q], wh[t][q], acc[t], 0, 0, 0);
      }
    float dv[4];
    if (DINV_OUT) {
#pragma unroll
      for (int r = 0; r < 4; ++r) {
        int row = row0 + quad * 4 + r;
        dv[r] = (row < n) ? dinv[row] : 0.0f;
      }
    }
#pragma unroll
    for (int t = 0; t < 4; ++t)
#pragma unroll
      for (int r = 0; r < 4; ++r) {
        int row = row0 + quad * 4 + r;
        if (row < n) {
          float v = acc[t][r] + bv[t];
          if (RELU_OUT) v = fmaxf(v, 0.0f);
          if (DINV_OUT) v *= dv[r];
          out[(size_t)row * 64 + t * 16 + col] = v;
        }
      }
  }
}

// One wave per node; 4 edge-slots x 16 lanes x float4; 2x unrolled so each
// slot keeps 2 independent row gathers in flight (8 per wave).
// out = relu(dinv[node] * (sum_src hws[src] + hws[node]) + bias)
__global__ void k_agg(const float* __restrict__ hws, const float* __restrict__ dinv,
                      const int* __restrict__ row_ptr, const int* __restrict__ srcs,
                      const float* __restrict__ bias, float* __restrict__ out, int n) {
  int wid = (blockIdx.x * blockDim.x + threadIdx.x) >> 6;
  if (wid >= n) return;
  int lane = threadIdx.x & 63;
  int slot = lane >> 4;  // 0..3
  int fg = lane & 15;    // float4 feature group
  const float4* hws4 = (const float4*)hws;

  int p0 = row_ptr[wid], p1 = row_ptr[wid + 1];
  float4 acc = make_float4(0.f, 0.f, 0.f, 0.f);
  int p = p0 + slot;
  while (p + 4 < p1) {  // 2 edges per iteration, both gathers independent
    int s0 = srcs[p];
    int s1 = srcs[p + 4];
    float4 v0 = hws4[(size_t)s0 * 16 + fg];
    float4 v1 = hws4[(size_t)s1 * 16 + fg];
    acc.x += v0.x + v1.x;
    acc.y += v0.y + v1.y;
    acc.z += v0.z + v1.z;
    acc.w += v0.w + v1.w;
    p += 8;
  }
  if (p < p1) {
    float4 v = hws4[(size_t)srcs[p] * 16 + fg];
    acc.x += v.x; acc.y += v.y; acc.z += v.z; acc.w += v.w;
  }
#pragma unroll
  for (int off = 16; off < 64; off <<= 1) {
    acc.x += __shfl_xor(acc.x, off);
    acc.y += __shfl_xor(acc.y, off);
    acc.z += __shfl_xor(acc.z, off);
    acc.w += __shfl_xor(acc.w, off);
  }
  if (slot == 0) {
    float di = dinv[wid];
    float4 selfv = hws4[(size_t)wid * 16 + fg];
    float4 b4 = ((const float4*)bias)[fg];
    float4 r;
    r.x = fmaxf(fmaf(di, acc.x + selfv.x, b4.x), 0.f);
    r.y = fmaxf(fmaf(di, acc.y + selfv.y, b4.y), 0.f);
    r.z = fmaxf(fmaf(di, acc.z + selfv.z, b4.z), 0.f);
    r.w = fmaxf(fmaf(di, acc.w + selfv.w, b4.w), 0.f);
    ((float4*)out)[(size_t)wid * 16 + fg] = r;
  }
}

extern "C" void kernel_launch(void* const* d_in, const int* in_sizes, int n_in,
                              void* d_out, int out_size, void* d_ws, size_t ws_size,
                              hipStream_t stream) {
  const float* x = (const float*)d_in[0];
  const int* ei = (const int*)d_in[1];  // int32 per harness convention
  const float* W1 = (const float*)d_in[2];
  const float* b1 = (const float*)d_in[3];
  const float* W2 = (const float*)d_in[4];
  const float* b2 = (const float*)d_in[5];
  const float* W3 = (const float*)d_in[6];
  const float* b3 = (const float*)d_in[7];
  const float* fw1 = (const float*)d_in[8];
  const float* fb1 = (const float*)d_in[9];
  const float* fw2 = (const float*)d_in[10];
  const float* fb2 = (const float*)d_in[11];
  float* out = (float*)d_out;

  const int N = in_sizes[0] / 64;
  const int E = in_sizes[1] / 2;

  // workspace (~31 MB); d_out doubles as ping-pong activation buffer
  char* w = (char*)d_ws;
  auto take = [&](size_t bytes) -> char* {
    char* p = w;
    w += (bytes + 255) & ~(size_t)255;
    return p;
  };
  float* dinv = (float*)take((size_t)N * 4);
  int* cursors = (int*)take((size_t)N * 4);
  int* row_ptr = (int*)take((size_t)(N + 1) * 4);
  int* bsums = (int*)take((size_t)SCAN_B * 4);
  int* srcs = (int*)take((size_t)E * 4);
  bf16x8* wpack = (bf16x8*)take((size_t)5 * 1024 * 16);  // 80 KB
  float* buf0 = (float*)take((size_t)N * 64 * 4);
  float* buf1 = out;  // fully overwritten by the final mm

  const int B = 256;
  const int nb_scan = CDIV(N, SCAN_B);

  // ---- weight prep + CSR build ----
  k_prep<<<5, 512, 0, stream>>>(W1, W2, W3, fw1, fw2, wpack);
  k_zero_i32<<<CDIV(N, B), B, 0, stream>>>(cursors, N);           // counts
  k_count<<<CDIV(E, B), B, 0, stream>>>(ei, cursors, E);
  k_scan1<<<nb_scan, SCAN_B, 0, stream>>>(cursors, row_ptr, bsums, dinv, N);
  k_scan2<<<1, SCAN_B, 0, stream>>>(bsums, nb_scan);
  k_scan3<<<CDIV(N, B), B, 0, stream>>>(row_ptr, bsums, cursors, N, E);
  k_fill<<<CDIV(E, B), B, 0, stream>>>(ei, cursors, srcs, E);

  const int ntiles = CDIV(N, 16);
  const int MMG = CDIV(CDIV(ntiles, 2), 4);  // 2 tiles/wave, 4 waves/block
  const int AGG_G = CDIV(N, 4);              // 1 node/wave

  // hws1 = (x@W1)*dinv
  k_mm<false, false, true><<<MMG, B, 0, stream>>>(x, wpack + 0 * 1024, nullptr, dinv, buf0, N);
  // h1 = relu(dinv*(agg+self) + b1)
  k_agg<<<AGG_G, B, 0, stream>>>(buf0, dinv, row_ptr, srcs, b1, buf1, N);
  // hws2 = (h1@W2)*dinv
  k_mm<false, false, true><<<MMG, B, 0, stream>>>(buf1, wpack + 1 * 1024, nullptr, dinv, buf0, N);
  k_agg<<<AGG_G, B, 0, stream>>>(buf0, dinv, row_ptr, srcs, b2, buf1, N);
  // hws3 = (h2@W3)*dinv
  k_mm<false, false, true><<<MMG, B, 0, stream>>>(buf1, wpack + 2 * 1024, nullptr, dinv, buf0, N);
  k_agg<<<AGG_G, B, 0, stream>>>(buf0, dinv, row_ptr, srcs, b3, buf1, N);
  // h4 = relu(h3@fw1 + fb1)
  k_mm<true, true, false><<<MMG, B, 0, stream>>>(buf1, wpack + 3 * 1024, fb1, nullptr, buf0, N);
  // out = h4@fw2 + fb2
  k_mm<true, false, false><<<MMG, B, 0, stream>>>(buf0, wpack + 4 * 1024, fb2, nullptr, out, N);
}

// Round 9
// 374.108 us; speedup vs baseline: 1.3166x; 1.2519x over previous
//
#include <hip/hip_runtime.h>
#include <cstdint>
#include <cstddef>

// GCN link prediction: 3x GCNConv(64->64) + ReLU, then 2-layer MLP head.
// N=100k, E=1M, dims 64. Round 9:
//  - hws gather tables stored BF16 (12.8 MB, 128 B rows = 1 cache line):
//    halves agg's L2-miss traffic. Accumulation stays fp32; agg outputs and
//    all mm A-inputs stay fp32 (split-bf16 MFMA).
//  - k_fill XCD-grouped: blockIdx%8 selects a dst-range so each srcs line is
//    written by ONE XCD's L2 (round-8 counters showed 17x write amplification
//    from cross-XCD partial-line writebacks).

#define CDIV(a, b) (((a) + (b) - 1) / (b))
static constexpr int SCAN_B = 1024;

typedef __attribute__((ext_vector_type(8))) short bf16x8;
typedef __attribute__((ext_vector_type(4))) float f32x4;

// Split a into hi (RNE bf16) + lo (truncated bf16 of exact residual).
__device__ __forceinline__ void split_bf(float a, short& hi, short& lo) {
  unsigned u = __float_as_uint(a);
  unsigned r = u + (0x7FFF + ((u >> 16) & 1));  // RNE round to bf16
  hi = (short)(r >> 16);
  float hirec = __uint_as_float(r & 0xFFFF0000u);
  float res = a - hirec;  // exact
  lo = (short)(__float_as_uint(res) >> 16);  // truncate
}

__device__ __forceinline__ unsigned short f2bf_rne(float a) {
  unsigned u = __float_as_uint(a);
  u += 0x7FFF + ((u >> 16) & 1);
  return (unsigned short)(u >> 16);
}

__device__ __forceinline__ float4 bf4_to_f4(uint2 u) {
  float4 v;
  v.x = __uint_as_float(u.x << 16);
  v.y = __uint_as_float(u.x & 0xFFFF0000u);
  v.z = __uint_as_float(u.y << 16);
  v.w = __uint_as_float(u.y & 0xFFFF0000u);
  return v;
}

__global__ void k_zero_i32(int* __restrict__ p, int n) {
  int i = blockIdx.x * blockDim.x + threadIdx.x;
  if (i < n) p[i] = 0;
}

__global__ void k_count(const int* __restrict__ ei, int* __restrict__ counts, int E) {
  int e = blockIdx.x * blockDim.x + threadIdx.x;
  if (e < E) atomicAdd(&counts[ei[E + e]], 1);
}

// Inclusive block scan -> exclusive output + per-block sums; also dinv.
__global__ void k_scan1(const int* __restrict__ counts, int* __restrict__ excl,
                        int* __restrict__ bsums, float* __restrict__ dinv, int n) {
  __shared__ int sh[SCAN_B];
  int t = threadIdx.x;
  int idx = blockIdx.x * SCAN_B + t;
  int v = (idx < n) ? counts[idx] : 0;
  if (idx < n) dinv[idx] = rsqrtf((float)v + 1.0f);
  int val = v;
  sh[t] = val;
  __syncthreads();
  for (int off = 1; off < SCAN_B; off <<= 1) {
    int add = (t >= off) ? sh[t - off] : 0;
    __syncthreads();
    val += add;
    sh[t] = val;
    __syncthreads();
  }
  if (idx < n) excl[idx] = val - v;
  if (t == SCAN_B - 1) bsums[blockIdx.x] = val;
}

__global__ void k_scan2(int* __restrict__ bsums, int nb) {
  __shared__ int sh[SCAN_B];
  int t = threadIdx.x;
  int v = (t < nb) ? bsums[t] : 0;
  int val = v;
  sh[t] = val;
  __syncthreads();
  for (int off = 1; off < SCAN_B; off <<= 1) {
    int add = (t >= off) ? sh[t - off] : 0;
    __syncthreads();
    val += add;
    sh[t] = val;
    __syncthreads();
  }
  if (t < nb) bsums[t] = val - v;
}

// Finalize row_ptr; init fill cursors to row_ptr.
__global__ void k_scan3(int* __restrict__ row_ptr, const int* __restrict__ bsums,
                        int* __restrict__ cursors, int n, int E) {
  int i = blockIdx.x * blockDim.x + threadIdx.x;
  if (i < n) {
    int rp = row_ptr[i] + bsums[i >> 10];  // SCAN_B == 1024
    row_ptr[i] = rp;
    cursors[i] = rp;
  }
  if (i == 0) row_ptr[n] = E;
}

// XCD-grouped scatter: group g = blockIdx%8 handles dst range g (N/8 nodes),
// so each srcs cache line is dirtied by a single XCD's L2 (blockIdx%8 is the
// XCD round-robin heuristic; wrong mapping only costs speed, not correctness).
__global__ void k_fill(const int* __restrict__ ei, int* __restrict__ cursors,
                       int* __restrict__ srcs, int E, int N) {
  int g = blockIdx.x & 7;
  int bi = blockIdx.x >> 3;
  int stride = (gridDim.x >> 3) * blockDim.x;
  int lo = (int)(((long long)N * g) >> 3);
  int hi = (int)(((long long)N * (g + 1)) >> 3);
  for (int e = bi * blockDim.x + threadIdx.x; e < E; e += stride) {
    int d = ei[E + e];
    if (d >= lo && d < hi) {
      int s = ei[e];
      int pos = atomicAdd(&cursors[d], 1);
      srcs[pos] = s;
    }
  }
}

// Pre-split 5 weight matrices (64x64, [in,out] row-major) into hi/lo bf16
// fragments, packed: packed[mat*1024 + ((t*2+q)*2+h)*64 + lane].
__global__ void k_prep(const float* __restrict__ w0, const float* __restrict__ w1,
                       const float* __restrict__ w2, const float* __restrict__ w3,
                       const float* __restrict__ w4, bf16x8* __restrict__ packed) {
  const float* W;
  switch (blockIdx.x) {
    case 0: W = w0; break;
    case 1: W = w1; break;
    case 2: W = w2; break;
    case 3: W = w3; break;
    default: W = w4; break;
  }
  int tid = threadIdx.x;  // 0..511
  int lane = tid & 63;
  int q = (tid >> 6) & 1;
  int t = tid >> 7;
  int col = lane & 15, quad = lane >> 4;
  bf16x8 hi8, lo8;
#pragma unroll
  for (int j = 0; j < 8; ++j) {
    int k = q * 32 + quad * 8 + j;
    short hi, lo;
    split_bf(W[k * 64 + t * 16 + col], hi, lo);
    hi8[j] = hi;
    lo8[j] = lo;
  }
  size_t base = (size_t)blockIdx.x * 1024 + ((t * 2 + q) * 2) * 64 + lane;
  packed[base] = hi8;
  packed[base + 64] = lo8;
}

// C[n x 64] = A @ W (+bias) (+relu) (optionally *dinv[row]); output fp32 or
// bf16 (gather-table producer). One 16-row tile per wave.
// Verified layouts: A[m=lane&15][k=quad*8+j]; B[k][n=lane&15];
// C col=lane&15, row=quad*4+reg.
template <bool HAS_BIAS, bool RELU_OUT, bool DINV_OUT, bool BF16_OUT>
__global__ __launch_bounds__(256, 4)
void k_mm(const float* __restrict__ in, const bf16x8* __restrict__ Wp,
          const float* __restrict__ bias, const float* __restrict__ dinv,
          void* __restrict__ out, int n) {
  int lane = threadIdx.x & 63;
  int col = lane & 15, quad = lane >> 4;
  int tile = (blockIdx.x * blockDim.x + threadIdx.x) >> 6;
  int ntiles = (n + 15) >> 4;
  if (tile >= ntiles) return;

  bf16x8 wh[4][2], wl[4][2];
#pragma unroll
  for (int t = 0; t < 4; ++t)
#pragma unroll
    for (int q = 0; q < 2; ++q) {
      wh[t][q] = Wp[((t * 2 + q) * 2) * 64 + lane];
      wl[t][q] = Wp[((t * 2 + q) * 2 + 1) * 64 + lane];
    }
  float bv[4];
#pragma unroll
  for (int t = 0; t < 4; ++t) bv[t] = HAS_BIAS ? bias[t * 16 + col] : 0.0f;

  int row0 = tile << 4;
  int ar = row0 + col;
  if (ar > n - 1) ar = n - 1;  // clamp; stores guarded
  const float4* arow = (const float4*)(in + (size_t)ar * 64 + quad * 8);
  float4 a0 = arow[0], a1 = arow[1], a2 = arow[8], a3 = arow[9];

  bf16x8 ah[2], al[2];
  {
    float av0[8] = {a0.x, a0.y, a0.z, a0.w, a1.x, a1.y, a1.z, a1.w};
    float av1[8] = {a2.x, a2.y, a2.z, a2.w, a3.x, a3.y, a3.z, a3.w};
#pragma unroll
    for (int j = 0; j < 8; ++j) {
      short hi, lo;
      split_bf(av0[j], hi, lo);
      ah[0][j] = hi; al[0][j] = lo;
      split_bf(av1[j], hi, lo);
      ah[1][j] = hi; al[1][j] = lo;
    }
  }
  f32x4 acc[4];
#pragma unroll
  for (int t = 0; t < 4; ++t) acc[t] = (f32x4){0.f, 0.f, 0.f, 0.f};
#pragma unroll
  for (int t = 0; t < 4; ++t)
#pragma unroll
    for (int q = 0; q < 2; ++q) {
      acc[t] = __builtin_amdgcn_mfma_f32_16x16x32_bf16(ah[q], wh[t][q], acc[t], 0, 0, 0);
      acc[t] = __builtin_amdgcn_mfma_f32_16x16x32_bf16(ah[q], wl[t][q], acc[t], 0, 0, 0);
      acc[t] = __builtin_amdgcn_mfma_f32_16x16x32_bf16(al[q], wh[t][q], acc[t], 0, 0, 0);
    }
  float dv[4];
  if (DINV_OUT) {
#pragma unroll
    for (int r = 0; r < 4; ++r) {
      int row = row0 + quad * 4 + r;
      dv[r] = (row < n) ? dinv[row] : 0.0f;
    }
  }
#pragma unroll
  for (int t = 0; t < 4; ++t)
#pragma unroll
    for (int r = 0; r < 4; ++r) {
      int row = row0 + quad * 4 + r;
      if (row < n) {
        float v = acc[t][r] + bv[t];
        if (RELU_OUT) v = fmaxf(v, 0.0f);
        if (DINV_OUT) v *= dv[r];
        if (BF16_OUT) {
          ((unsigned short*)out)[(size_t)row * 64 + t * 16 + col] = f2bf_rne(v);
        } else {
          ((float*)out)[(size_t)row * 64 + t * 16 + col] = v;
        }
      }
    }
}

// One wave per node; 4 edge-slots x 16 lanes x 4 bf16 (8 B); 2x unrolled so
// 8 independent 128 B row gathers are in flight per wave.
// out = relu(dinv[node] * (sum_src hws[src] + hws[node]) + bias), fp32.
__global__ void k_agg(const unsigned short* __restrict__ hws, const float* __restrict__ dinv,
                      const int* __restrict__ row_ptr, const int* __restrict__ srcs,
                      const float* __restrict__ bias, float* __restrict__ out, int n) {
  int wid = (blockIdx.x * blockDim.x + threadIdx.x) >> 6;
  if (wid >= n) return;
  int lane = threadIdx.x & 63;
  int slot = lane >> 4;  // 0..3
  int fg = lane & 15;    // 4-bf16 feature group
  const uint2* hw2 = (const uint2*)hws;  // row = 16 x uint2

  int p0 = row_ptr[wid], p1 = row_ptr[wid + 1];
  float4 acc = make_float4(0.f, 0.f, 0.f, 0.f);
  int p = p0 + slot;
  while (p + 4 < p1) {
    int s0 = srcs[p];
    int s1 = srcs[p + 4];
    uint2 u0 = hw2[(size_t)s0 * 16 + fg];
    uint2 u1 = hw2[(size_t)s1 * 16 + fg];
    float4 v0 = bf4_to_f4(u0);
    float4 v1 = bf4_to_f4(u1);
    acc.x += v0.x + v1.x;
    acc.y += v0.y + v1.y;
    acc.z += v0.z + v1.z;
    acc.w += v0.w + v1.w;
    p += 8;
  }
  if (p < p1) {
    float4 v = bf4_to_f4(hw2[(size_t)srcs[p] * 16 + fg]);
    acc.x += v.x; acc.y += v.y; acc.z += v.z; acc.w += v.w;
  }
#pragma unroll
  for (int off = 16; off < 64; off <<= 1) {
    acc.x += __shfl_xor(acc.x, off);
    acc.y += __shfl_xor(acc.y, off);
    acc.z += __shfl_xor(acc.z, off);
    acc.w += __shfl_xor(acc.w, off);
  }
  if (slot == 0) {
    float di = dinv[wid];
    float4 selfv = bf4_to_f4(hw2[(size_t)wid * 16 + fg]);
    float4 b4 = ((const float4*)bias)[fg];
    float4 r;
    r.x = fmaxf(fmaf(di, acc.x + selfv.x, b4.x), 0.f);
    r.y = fmaxf(fmaf(di, acc.y + selfv.y, b4.y), 0.f);
    r.z = fmaxf(fmaf(di, acc.z + selfv.z, b4.z), 0.f);
    r.w = fmaxf(fmaf(di, acc.w + selfv.w, b4.w), 0.f);
    ((float4*)out)[(size_t)wid * 16 + fg] = r;
  }
}

extern "C" void kernel_launch(void* const* d_in, const int* in_sizes, int n_in,
                              void* d_out, int out_size, void* d_ws, size_t ws_size,
                              hipStream_t stream) {
  const float* x = (const float*)d_in[0];
  const int* ei = (const int*)d_in[1];  // int32 per harness convention
  const float* W1 = (const float*)d_in[2];
  const float* b1 = (const float*)d_in[3];
  const float* W2 = (const float*)d_in[4];
  const float* b2 = (const float*)d_in[5];
  const float* W3 = (const float*)d_in[6];
  const float* b3 = (const float*)d_in[7];
  const float* fw1 = (const float*)d_in[8];
  const float* fb1 = (const float*)d_in[9];
  const float* fw2 = (const float*)d_in[10];
  const float* fb2 = (const float*)d_in[11];
  float* out = (float*)d_out;

  const int N = in_sizes[0] / 64;
  const int E = in_sizes[1] / 2;

  // workspace (~44 MB); d_out doubles as an fp32 activation buffer
  char* w = (char*)d_ws;
  auto take = [&](size_t bytes) -> char* {
    char* p = w;
    w += (bytes + 255) & ~(size_t)255;
    return p;
  };
  float* dinv = (float*)take((size_t)N * 4);
  int* cursors = (int*)take((size_t)N * 4);
  int* row_ptr = (int*)take((size_t)(N + 1) * 4);
  int* bsums = (int*)take((size_t)SCAN_B * 4);
  int* srcs = (int*)take((size_t)E * 4);
  bf16x8* wpack = (bf16x8*)take((size_t)5 * 1024 * 16);         // 80 KB
  unsigned short* hws = (unsigned short*)take((size_t)N * 64 * 2);  // 12.8 MB
  float* buf0 = (float*)take((size_t)N * 64 * 4);               // 25.6 MB
  float* buf1 = out;  // fully overwritten by the final mm

  const int B = 256;
  const int nb_scan = CDIV(N, SCAN_B);

  // ---- weight prep + CSR build ----
  k_prep<<<5, 512, 0, stream>>>(W1, W2, W3, fw1, fw2, wpack);
  k_zero_i32<<<CDIV(N, B), B, 0, stream>>>(cursors, N);  // counts
  k_count<<<CDIV(E, B), B, 0, stream>>>(ei, cursors, E);
  k_scan1<<<nb_scan, SCAN_B, 0, stream>>>(cursors, row_ptr, bsums, dinv, N);
  k_scan2<<<1, SCAN_B, 0, stream>>>(bsums, nb_scan);
  k_scan3<<<CDIV(N, B), B, 0, stream>>>(row_ptr, bsums, cursors, N, E);
  k_fill<<<4096, B, 0, stream>>>(ei, cursors, srcs, E, N);  // 8 XCD groups x 512 blocks

  const int ntiles = CDIV(N, 16);
  const int MMG = CDIV(ntiles, 4);  // 1 tile/wave, 4 waves/block
  const int AGG_G = CDIV(N, 4);     // 1 node/wave

  // hws1 = bf16((x@W1)*dinv)
  k_mm<false, false, true, true><<<MMG, B, 0, stream>>>(x, wpack + 0 * 1024, nullptr, dinv, hws, N);
  // h1 = relu(dinv*(agg+self) + b1)  [fp32, d_out]
  k_agg<<<AGG_G, B, 0, stream>>>(hws, dinv, row_ptr, srcs, b1, buf1, N);
  // hws2 = bf16((h1@W2)*dinv)
  k_mm<false, false, true, true><<<MMG, B, 0, stream>>>(buf1, wpack + 1 * 1024, nullptr, dinv, hws, N);
  // h2 -> buf0
  k_agg<<<AGG_G, B, 0, stream>>>(hws, dinv, row_ptr, srcs, b2, buf0, N);
  // hws3 = bf16((h2@W3)*dinv)
  k_mm<false, false, true, true><<<MMG, B, 0, stream>>>(buf0, wpack + 2 * 1024, nullptr, dinv, hws, N);
  // h3 -> d_out
  k_agg<<<AGG_G, B, 0, stream>>>(hws, dinv, row_ptr, srcs, b3, buf1, N);
  // h4 = relu(h3@fw1 + fb1) -> buf0 [fp32]
  k_mm<true, true, false, false><<<MMG, B, 0, stream>>>(buf1, wpack + 3 * 1024, fb1, nullptr, buf0, N);
  // out = h4@fw2 + fb2 -> d_out [fp32]
  k_mm<true, false, false, false><<<MMG, B, 0, stream>>>(buf0, wpack + 4 * 1024, fb2, nullptr, out, N);
}